// Round 12
// baseline (139.805 us; speedup 1.0000x reference)
//
#include <hip/hip_runtime.h>

#define NBINS 256
#define TPB 256
#define NCOPY 4       // one copy per wave
#define CSTRIDE 264   // 256 bins + dummy slot(256) + pad; copies bank-rotate by 8

typedef float f32x4 __attribute__((ext_vector_type(4)));

__global__ void zero_out_kernel(float* __restrict__ out) {
    out[threadIdx.x] = 0.0f;
}

// ---------------- hist kernel: R11 verbatim (76.3 us known) ----------------
__global__ __launch_bounds__(TPB) void hist_kernel(const float* __restrict__ x,
                                                   float* __restrict__ out,
                                                   int n) {
    __shared__ int lh[NCOPY * CSTRIDE];
    const int tid = threadIdx.x;
    int* __restrict__ myh = &lh[(tid >> 6) * CSTRIDE];

    for (int i = tid; i < NCOPY * CSTRIDE; i += TPB)
        lh[i] = 0;
    __syncthreads();

    const int gid    = blockIdx.x * TPB + tid;
    const int stride = gridDim.x * TPB;
    const int n4     = n >> 2;
    const f32x4* __restrict__ x4 = (const f32x4*)x;

#define PROC(f) {                                        \
        float _t = __builtin_fmaf((f), 32.0f, 128.0f);   \
        unsigned _u = (unsigned)_t;                      \
        _u = _u > 255u ? 255u : _u;                      \
        bool _ok = __builtin_fabsf(f) <= 4.0f;           \
        int _b = _ok ? (int)_u : 256;                    \
        atomicAdd(&myh[_b], 1);                          \
    }
#define PROC4(a) { PROC(a.x) PROC(a.y) PROC(a.z) PROC(a.w) }

    const int iters = n4 / (8 * stride);

    if (iters > 0) {
        int i = gid;
        f32x4 a = x4[i];
        f32x4 b = x4[i + stride];
        f32x4 c = x4[i + 2 * stride];
        f32x4 d = x4[i + 3 * stride];
        f32x4 e = x4[i + 4 * stride];
        f32x4 f = x4[i + 5 * stride];
        f32x4 g = x4[i + 6 * stride];
        f32x4 h = x4[i + 7 * stride];
        for (int t = 1; t < iters; ++t) {
            const int ni = i + 8 * stride;
            f32x4 na = x4[ni];
            f32x4 nb = x4[ni + stride];
            f32x4 nc = x4[ni + 2 * stride];
            f32x4 nd = x4[ni + 3 * stride];
            f32x4 ne = x4[ni + 4 * stride];
            f32x4 nf = x4[ni + 5 * stride];
            f32x4 ng = x4[ni + 6 * stride];
            f32x4 nh = x4[ni + 7 * stride];
            PROC4(a) PROC4(b) PROC4(c) PROC4(d)
            PROC4(e) PROC4(f) PROC4(g) PROC4(h)
            a = na; b = nb; c = nc; d = nd;
            e = ne; f = nf; g = ng; h = nh;
            i = ni;
        }
        PROC4(a) PROC4(b) PROC4(c) PROC4(d)
        PROC4(e) PROC4(f) PROC4(g) PROC4(h)
    }

    for (int i2 = iters * 8 * stride + gid; i2 < n4; i2 += stride) {
        f32x4 a = x4[i2];
        PROC4(a)
    }
    for (int j = (n4 << 2) + gid; j < n; j += stride) {
        float f2 = x[j];
        PROC(f2)
    }
#undef PROC4
#undef PROC

    __syncthreads();

    int s = lh[0 * CSTRIDE + tid] + lh[1 * CSTRIDE + tid] +
            lh[2 * CSTRIDE + tid] + lh[3 * CSTRIDE + tid];
    if (s)
        atomicAdd(&out[tid], (float)s);
}

// ---------------- probe 1: load-only, identical pattern ----------------
__global__ __launch_bounds__(TPB) void probe_load_kernel(const float* __restrict__ x,
                                                         int n) {
    const int tid    = threadIdx.x;
    const int gid    = blockIdx.x * TPB + tid;
    const int stride = gridDim.x * TPB;
    const int n4     = n >> 2;
    const f32x4* __restrict__ x4 = (const f32x4*)x;

    const int iters = n4 / (8 * stride);
    f32x4 acc = {0.f, 0.f, 0.f, 0.f};
    int i = gid;
    for (int t = 0; t < iters; ++t) {
        f32x4 a = x4[i];
        f32x4 b = x4[i + stride];
        f32x4 c = x4[i + 2 * stride];
        f32x4 d = x4[i + 3 * stride];
        f32x4 e = x4[i + 4 * stride];
        f32x4 f = x4[i + 5 * stride];
        f32x4 g = x4[i + 6 * stride];
        f32x4 h = x4[i + 7 * stride];
        acc += a + b + c + d + e + f + g + h;
        i += 8 * stride;
    }
    // keep the loads alive without any memory side-effect
    asm volatile("" :: "v"(acc.x), "v"(acc.y), "v"(acc.z), "v"(acc.w));
}

// ---------------- probe 2: DS-atomic-only, same count & layout ----------------
__global__ __launch_bounds__(TPB) void probe_ds_kernel(float* __restrict__ ws,
                                                       int per_thread) {
    __shared__ int lh[NCOPY * CSTRIDE];
    const int tid = threadIdx.x;
    int* __restrict__ myh = &lh[(tid >> 6) * CSTRIDE];

    for (int i = tid; i < NCOPY * CSTRIDE; i += TPB)
        lh[i] = 0;
    __syncthreads();

    // 4 independent LCG streams -> 4 atomics per unrolled step, bins uniform
    // over [0,256). 2 VALU per atomic; no VMEM. Atomic count per thread =
    // per_thread (128 for the canonical shape) == hist kernel's element count.
    unsigned u0 = (blockIdx.x * TPB + tid) * 2654435761u + 1u;
    unsigned u1 = u0 ^ 0x9E3779B9u;
    unsigned u2 = u0 + 0x85EBCA6Bu;
    unsigned u3 = u0 ^ 0xC2B2AE35u;
    const int steps = per_thread >> 2;
    for (int t = 0; t < steps; ++t) {
        u0 = u0 * 1664525u + 1013904223u;
        u1 = u1 * 1664525u + 1013904223u;
        u2 = u2 * 1664525u + 1013904223u;
        u3 = u3 * 1664525u + 1013904223u;
        atomicAdd(&myh[(u0 >> 10) & 255u], 1);
        atomicAdd(&myh[(u1 >> 10) & 255u], 1);
        atomicAdd(&myh[(u2 >> 10) & 255u], 1);
        atomicAdd(&myh[(u3 >> 10) & 255u], 1);
    }
    __syncthreads();

    // observe LDS so the atomics can't be considered dead; sink via asm.
    int s = lh[tid] + lh[tid + 1024];
    asm volatile("" :: "v"(s));
    (void)ws;
}

extern "C" void kernel_launch(void* const* d_in, const int* in_sizes, int n_in,
                              void* d_out, int out_size, void* d_ws, size_t ws_size,
                              hipStream_t stream) {
    const float* x = (const float*)d_in[0];
    float* out = (float*)d_out;
    const int n = in_sizes[0];

    zero_out_kernel<<<1, NBINS, 0, stream>>>(out);

    int n4 = n >> 2;
    long long want = ((long long)n4 + (long long)TPB * 8 - 1) / ((long long)TPB * 8);
    int blocks = (int)(want < 1 ? 1 : (want > 2048 ? 2048 : want));
    hist_kernel<<<blocks, TPB, 0, stream>>>(x, out, n);

    // ---- ablation probes (timing-only; do not touch d_out) ----
    probe_load_kernel<<<blocks, TPB, 0, stream>>>(x, n);
    int per_thread = (int)(((long long)n) / ((long long)blocks * TPB));
    if (per_thread < 4) per_thread = 4;
    probe_ds_kernel<<<blocks, TPB, 0, stream>>>((float*)d_ws, per_thread);
}